// Round 11
// baseline (89.206 us; speedup 1.0000x reference)
//
#include <hip/hip_runtime.h>
#include <stdint.h>

// GraphCut fused contrastive loss, MI355X (gfx950) — round 11.
// loss = -mean_i( sum_{j!=i} sign_ij * exp(sim_ij - rowmax_i) ), sim = (F F^T)/0.2.
// History: R3 serial 47us | R5 LDS dbuf+barrier/tile 82us | R6 2-deep reg
// pipeline ~36us | R7 2-A-tiles 54us | R8 full-unroll 42us | R10 fp8 ~36us
// (NEUTRAL vs bf16 -> L2-BW theory falsified; binder = global latency in loop).
// R11: whole 64-KB fp8 B panel staged to LDS once, ONE barrier, K-loop is pure
// ds_read+MFMA (no global loads, no barriers, no vmcnt in the loop).

#define M_ROWS 8192
#define K_DIM  128
#define NCHUNK 16
#define CHUNK_COLS (M_ROWS / NCHUNK)      // 512
#define NT_PER_CHUNK (CHUNK_COLS / 32)    // 16
#define PANEL_BYTES (CHUNK_COLS * K_DIM)  // 64 KB fp8
#define INV_T_LOG2E 7.213475204444817f    // (1/0.2) * log2(e)

typedef float f32x16 __attribute__((ext_vector_type(16)));
typedef long  lx2    __attribute__((ext_vector_type(2)));   // 16 B = two fp8 K-slices

// FB8 layout: 16-B granule index = ((ct*4 + sp)*2 + l5)*32 + lm holding fp8
// F[ct*32 + lm][k], k = 32*sp + 8*l5 + {0..7} (low 8 B) and +16 (high 8 B).
// One col-tile ct = 256 granules = 4 KB contiguous; a chunk's panel = 64 KB
// contiguous — staged linearly to LDS, read back with the same indexing.

__device__ __forceinline__ float fp8_sumsq(int w) {
    float v0 = __builtin_amdgcn_cvt_f32_fp8(w, 0);
    float v1 = __builtin_amdgcn_cvt_f32_fp8(w, 1);
    float v2 = __builtin_amdgcn_cvt_f32_fp8(w, 2);
    float v3 = __builtin_amdgcn_cvt_f32_fp8(w, 3);
    return v0 * v0 + v1 * v1 + v2 * v2 + v3 * v3;
}

// ---- prep: fp32 -> fp8 e4m3 into fragment layout + per-row self-dot ----
// Self-dot computed from the DEQUANTIZED fp8 values so the online-softmax
// init matches exactly what the MFMA computes on the diagonal.
__global__ __launch_bounds__(256) void prep_kernel(const float* __restrict__ f,
                                                   int4* __restrict__ FB8,
                                                   float* __restrict__ selfdot,
                                                   float* __restrict__ out) {
    const int t   = threadIdx.x;
    const int row = blockIdx.x * 32 + (t >> 3);
    const int sub = t & 7;            // 8 threads per row
    const int sp  = sub >> 1;         // K-slice pair 0..3
    const int l5  = sub & 1;
    const float4* fr = (const float4*)(f + (size_t)row * K_DIM);
    const float4 a0 = fr[8 * sp + 2 * l5];
    const float4 a1 = fr[8 * sp + 2 * l5 + 1];
    const float4 b0 = fr[8 * sp + 2 * l5 + 4];   // +16 elements
    const float4 b1 = fr[8 * sp + 2 * l5 + 5];
    int w0 = __builtin_amdgcn_cvt_pk_fp8_f32(a0.x, a0.y, 0, false);
    w0     = __builtin_amdgcn_cvt_pk_fp8_f32(a0.z, a0.w, w0, true);
    int w1 = __builtin_amdgcn_cvt_pk_fp8_f32(a1.x, a1.y, 0, false);
    w1     = __builtin_amdgcn_cvt_pk_fp8_f32(a1.z, a1.w, w1, true);
    int w2 = __builtin_amdgcn_cvt_pk_fp8_f32(b0.x, b0.y, 0, false);
    w2     = __builtin_amdgcn_cvt_pk_fp8_f32(b0.z, b0.w, w2, true);
    int w3 = __builtin_amdgcn_cvt_pk_fp8_f32(b1.x, b1.y, 0, false);
    w3     = __builtin_amdgcn_cvt_pk_fp8_f32(b1.z, b1.w, w3, true);
    float ss = fp8_sumsq(w0) + fp8_sumsq(w1) + fp8_sumsq(w2) + fp8_sumsq(w3);
#pragma unroll
    for (int off = 1; off < 8; off <<= 1) ss += __shfl_xor(ss, off, 64);
    if (sub == 0) selfdot[row] = ss;
    const int ct = row >> 5, lm = row & 31;
    int4 st = {w0, w1, w2, w3};
    FB8[(size_t)(((ct * 4 + sp) * 2 + l5)) * 32 + lm] = st;
    if (blockIdx.x == 0 && t == 0) out[0] = 0.f;   // d_out is poisoned 0xAA
}

// async 16-B global->LDS copy (per-lane src addr; LDS dst = uniform base + lane*16)
__device__ __forceinline__ void async_cp16(const void* src, void* lds_dst) {
    __builtin_amdgcn_global_load_lds(
        (const __attribute__((address_space(1))) unsigned int*)src,
        (__attribute__((address_space(3))) unsigned int*)lds_dst, 16, 0, 0);
}

// ---- main fused kernel: 1024 blocks = 64 row-groups(128 rows) x 16 chunks ----
// Block = 4 waves; full 64-KB B panel staged to LDS once; one barrier; K-loop
// is ds_read_b128 + MFMA + amax only.
__global__ __launch_bounds__(256) void fused_kernel(const int4* __restrict__ FB8,
                                                    const int* __restrict__ labels,
                                                    const float* __restrict__ selfdot,
                                                    float* __restrict__ partials) {
    __shared__ char lds[PANEL_BYTES];
    const int blk  = blockIdx.x;
    const int rg   = blk >> 4;          // row group (128 rows)
    const int ch   = blk & 15;          // col chunk (512 cols)
    const int tid  = threadIdx.x;
    const int w    = tid >> 6;
    const int lane = tid & 63;
    const int lm   = lane & 31;
    const int l5   = lane >> 5;
    const int row0 = rg * 128 + w * 32;
    const int ct0  = row0 >> 5;
    const int ctb0 = ch * NT_PER_CHUNK;
    const lx2* FB  = (const lx2*)FB8;
    const char* FBb = (const char*)FB8;

    // stage the whole panel: 16 issues x 256 threads x 16 B = 64 KB (linear)
#pragma unroll
    for (int i = 0; i < 16; ++i)
        async_cp16(FBb + (size_t)ctb0 * 4096 + (i * 256 + tid) * 16,
                   lds + i * 4096 + w * 1024);

    // resident A fragments: 4 slice-pairs (coalesced 1-KB wave loads) —
    // issued after staging so all latencies overlap before the one barrier
    lx2 af[4];
#pragma unroll
    for (int sp = 0; sp < 4; ++sp)
        af[sp] = FB[(size_t)((ct0 * 4 + sp) * 2 + l5) * 32 + lm];

    // online-softmax state per owned C-row (C/D layout: row = (r&3)+8*(r>>2)+4*l5)
    float m[16], s[16];
    float minm = 1e30f;
#pragma unroll
    for (int r = 0; r < 16; ++r) {
        m[r] = selfdot[row0 + (r & 3) + 8 * (r >> 2) + 4 * l5];  // diag dot ~ row max
        s[r] = 0.f;
        minm = fminf(minm, m[r]);
    }

    __syncthreads();   // panel landed (barrier drains vmcnt); only barrier in kernel

    auto ds_loadB = [&](int nt, lx2* dst) {
#pragma unroll
        for (int sp = 0; sp < 4; ++sp)
            dst[sp] = *(const lx2*)(lds + (((nt * 4 + sp) * 2 + l5) * 32 + lm) * 16);
    };

    auto computeTile = [&](int nt, const lx2* bf) {
        f32x16 acc = {};
#pragma unroll
        for (int sp = 0; sp < 4; ++sp) {
            acc = __builtin_amdgcn_mfma_f32_32x32x16_fp8_fp8(af[sp].x, bf[sp].x, acc, 0, 0, 0);
            acc = __builtin_amdgcn_mfma_f32_32x32x16_fp8_fp8(af[sp].y, bf[sp].y, acc, 0, 0, 0);
        }
        float amax = acc[0];
#pragma unroll
        for (int r = 1; r < 16; ++r) amax = fmaxf(amax, acc[r]);
        // wave-uniform skip: exp((acc-m)/T) == 0 in fp32 when acc - m < -21
        if (__any(amax > minm - 22.f)) {
            const int jcol = (ctb0 + nt) * 32 + lm;
            const int labj = labels[jcol];
#pragma unroll
            for (int r = 0; r < 16; ++r) {
                const int grow = row0 + (r & 3) + 8 * (r >> 2) + 4 * l5;
                float d    = acc[r] - m[r];
                float sign = (labj == labels[grow]) ? 1.f : -1.f;
                if (jcol == grow) sign = 0.f;              // mask diagonal
                bool  p = d > 0.f;
                float e = exp2f(fminf(d, -d) * INV_T_LOG2E);
                float xx = p ? s[r] : sign;
                float yy = p ? sign : s[r];
                s[r] = fmaf(xx, e, yy);                    // online rescale-or-add
                m[r] = fmaxf(m[r], acc[r]);
            }
            minm = m[0];
#pragma unroll
            for (int r = 1; r < 16; ++r) minm = fminf(minm, m[r]);
        }
    };

    // 2-deep ds_read pipeline (rolled x2 body; R8 showed full unroll hurts)
    lx2 b0[4], b1[4];
    ds_loadB(0, b0);
    for (int nt = 0; nt < NT_PER_CHUNK; nt += 2) {
        ds_loadB(nt + 1, b1);
        computeTile(nt, b0);
        if (nt + 2 < NT_PER_CHUNK) ds_loadB(nt + 2, b0);
        computeTile(nt + 1, b1);
    }

    // merge the 32 column-lane partials of each row (offs stay within l5 half)
#pragma unroll
    for (int off = 1; off < 32; off <<= 1) {
#pragma unroll
        for (int r = 0; r < 16; ++r) {
            float mo = __shfl_xor(m[r], off, 64);
            float so = __shfl_xor(s[r], off, 64);
            float d  = mo - m[r];
            bool  p  = d > 0.f;
            float e  = exp2f(fminf(d, -d) * INV_T_LOG2E);
            s[r] = p ? fmaf(s[r], e, so) : fmaf(so, e, s[r]);
            m[r] = fmaxf(m[r], mo);
        }
    }
    if (lm == 0) {
#pragma unroll
        for (int r = 0; r < 16; ++r) {
            const int grow = row0 + (r & 3) + 8 * (r >> 2) + 4 * l5;
            float* p = partials + ((size_t)grow * NCHUNK + ch) * 2;
            p[0] = m[r];
            p[1] = s[r];
        }
    }
}

// ---- merge chunk-partials per row, reduce, atomic add ----
__global__ __launch_bounds__(256) void merge_kernel(const float* __restrict__ partials,
                                                    float* __restrict__ out) {
    const int g = blockIdx.x * 256 + threadIdx.x;    // row id
    float M = -1e30f, S = 0.f;
#pragma unroll
    for (int c = 0; c < NCHUNK; ++c) {
        const float* p = partials + ((size_t)g * NCHUNK + c) * 2;
        float mo = p[0], so = p[1];
        float d  = mo - M;
        bool  pr = d > 0.f;
        float e  = exp2f(fminf(d, -d) * INV_T_LOG2E);
        S = pr ? fmaf(S, e, so) : fmaf(so, e, S);
        M = fmaxf(M, mo);
    }
    float val = -S * (1.0f / 8192.0f);
#pragma unroll
    for (int off = 1; off < 64; off <<= 1) val += __shfl_xor(val, off, 64);
    __shared__ float red[4];
    if ((threadIdx.x & 63) == 0) red[threadIdx.x >> 6] = val;
    __syncthreads();
    if (threadIdx.x == 0) atomicAdd(out, red[0] + red[1] + red[2] + red[3]);
}

extern "C" void kernel_launch(void* const* d_in, const int* in_sizes, int n_in,
                              void* d_out, int out_size, void* d_ws, size_t ws_size,
                              hipStream_t stream) {
    const float* feat   = (const float*)d_in[0];
    const int*   labels = (const int*)d_in[1];
    float*       out    = (float*)d_out;
    char*        ws     = (char*)d_ws;

    int4*  FB8      = (int4*)ws;                                                 // 1 MB fp8
    float* selfdot  = (float*)(ws + (size_t)M_ROWS * K_DIM);                     // 32 KB
    float* partials = (float*)(ws + (size_t)M_ROWS * K_DIM + M_ROWS * 4);        // 1 MB

    prep_kernel<<<M_ROWS / 32, 256, 0, stream>>>(feat, FB8, selfdot, out);
    fused_kernel<<<(M_ROWS / 128) * NCHUNK, 256, 0, stream>>>(FB8, labels, selfdot, partials);
    merge_kernel<<<M_ROWS / 256, 256, 0, stream>>>(partials, out);
}